// Round 1
// baseline (369.996 us; speedup 1.0000x reference)
//
#include <hip/hip_runtime.h>

// Problem constants (from reference)
#define V_ 12
#define N_ 80000
#define C_ 256
#define H_ 128
#define W_ 128
#define G_ 4096
#define M_ 512
#define E_ 200000
#define L_ 20
#define HD 128   // C/2 hidden dim

// Kernel 1: for each group g, gather its center point's fused feature
// (weighted mean over views of img_feat[v, :, y, x]) and atomically
// accumulate into per-mask sums msum[m] / counts mcnt[m].
__global__ void gather_mask_kernel(const float* __restrict__ img,
                                   const float* __restrict__ is_seen,
                                   const int* __restrict__ coords,
                                   const int* __restrict__ centers,
                                   const int* __restrict__ g2m,
                                   float* __restrict__ msum,
                                   float* __restrict__ mcnt) {
  int g = blockIdx.x;        // 0..G-1
  int c = threadIdx.x;       // 0..C-1
  int n = centers[g];
  int m = g2m[g];
  float acc = 0.f, wsum = 0.f;
#pragma unroll
  for (int v = 0; v < V_; ++v) {
    int x = coords[((size_t)v * N_ + n) * 2 + 0];
    int y = coords[((size_t)v * N_ + n) * 2 + 1];
    float w = is_seen[(size_t)v * N_ + n];
    float f = img[(((size_t)v * C_ + c) * H_ + y) * W_ + x];
    acc += f * w;
    wsum += w;
  }
  float val = acc / (wsum + 1e-6f);
  atomicAdd(&msum[(size_t)m * C_ + c], val);
  if (c == 0) atomicAdd(&mcnt[m], 1.0f);
}

// Kernel 2: mW1[m] = (where(mcnt>0, msum/max(mcnt,1), 0)) @ W1   (512 x 128)
__global__ void maskw1_kernel(const float* __restrict__ msum,
                              const float* __restrict__ mcnt,
                              const float* __restrict__ W1,
                              float* __restrict__ mW1) {
  int m = blockIdx.x;        // 0..M-1
  int j = threadIdx.x;       // 0..HD-1
  __shared__ float row[C_];
  row[j] = msum[(size_t)m * C_ + j];
  row[j + HD] = msum[(size_t)m * C_ + j + HD];
  __syncthreads();
  float cv = mcnt[m];
  float inv = cv > 0.f ? 1.0f / fmaxf(cv, 1.0f) : 0.f;
  float acc = 0.f;
  for (int c = 0; c < C_; ++c) {
    acc += row[c] * W1[(size_t)c * HD + j];
  }
  mW1[(size_t)m * HD + j] = acc * inv;
}

// Kernel 3: scatter pairs: fsum[p] += mW1[pair_mask[e]] ; cnt[p] += 1
__global__ void scatter_kernel(const int* __restrict__ pair_mask,
                               const int* __restrict__ pair_point,
                               const float* __restrict__ mW1,
                               float* __restrict__ fsum,
                               float* __restrict__ cnt) {
  int e = blockIdx.x;        // 0..E-1
  int j = threadIdx.x;       // 0..HD-1
  int m = pair_mask[e];
  int p = pair_point[e];
  atomicAdd(&fsum[(size_t)p * HD + j], mW1[(size_t)m * HD + j]);
  if (j == 0) atomicAdd(&cnt[p], 1.0f);
}

// Kernel 4: per-point epilogue: h = relu(fsum/cnt + b1); out = h @ W2 + b2
__global__ void mlp_kernel(const float* __restrict__ fsum,
                           const float* __restrict__ cnt,
                           const float* __restrict__ b1,
                           const float* __restrict__ W2,
                           const float* __restrict__ b2,
                           float* __restrict__ out) {
  int n = blockIdx.x * blockDim.x + threadIdx.x;
  if (n >= N_) return;
  float invc = 1.0f / fmaxf(cnt[n], 1e-6f);
  float o[L_];
#pragma unroll
  for (int l = 0; l < L_; ++l) o[l] = b2[l];
  const float* xr = &fsum[(size_t)n * HD];
#pragma unroll 4
  for (int k = 0; k < HD; ++k) {
    float h = fmaxf(xr[k] * invc + b1[k], 0.f);
#pragma unroll
    for (int l = 0; l < L_; ++l) o[l] += h * W2[k * L_ + l];
  }
  float* dst = &out[(size_t)n * L_];
#pragma unroll
  for (int l = 0; l < L_; ++l) dst[l] = o[l];
}

extern "C" void kernel_launch(void* const* d_in, const int* in_sizes, int n_in,
                              void* d_out, int out_size, void* d_ws, size_t ws_size,
                              hipStream_t stream) {
  const float* img      = (const float*)d_in[0];
  const float* is_seen  = (const float*)d_in[1];
  const float* W1       = (const float*)d_in[2];
  const float* b1       = (const float*)d_in[3];
  const float* W2       = (const float*)d_in[4];
  const float* b2       = (const float*)d_in[5];
  const int* coords     = (const int*)d_in[6];
  const int* centers    = (const int*)d_in[7];
  const int* g2m        = (const int*)d_in[8];
  const int* pair_mask  = (const int*)d_in[9];
  const int* pair_point = (const int*)d_in[10];
  float* out = (float*)d_out;

  // Workspace layout (floats): msum[M*C] | mcnt[M] | mW1[M*HD] | fsum[N*HD] | cnt[N]
  float* ws   = (float*)d_ws;
  float* msum = ws;
  float* mcnt = msum + (size_t)M_ * C_;
  float* mW1  = mcnt + M_;
  float* fsum = mW1 + (size_t)M_ * HD;
  float* cnt  = fsum + (size_t)N_ * HD;

  // Zero the accumulators (graph-capture-safe stream memsets; must run every call)
  hipMemsetAsync(msum, 0, ((size_t)M_ * C_ + M_) * sizeof(float), stream);
  hipMemsetAsync(fsum, 0, ((size_t)N_ * HD + N_) * sizeof(float), stream);

  gather_mask_kernel<<<G_, C_, 0, stream>>>(img, is_seen, coords, centers, g2m, msum, mcnt);
  maskw1_kernel<<<M_, HD, 0, stream>>>(msum, mcnt, W1, mW1);
  scatter_kernel<<<E_, HD, 0, stream>>>(pair_mask, pair_point, mW1, fsum, cnt);
  mlp_kernel<<<(N_ + 255) / 256, 256, 0, stream>>>(fsum, cnt, b1, W2, b2, out);
}

// Round 2
// 339.098 us; speedup vs baseline: 1.0911x; 1.0911x over previous
//
#include <hip/hip_runtime.h>

// Problem constants (from reference)
#define V_ 12
#define N_ 80000
#define C_ 256
#define H_ 128
#define W_ 128
#define G_ 4096
#define M_ 512
#define E_ 200000
#define L_ 20
#define HD 128   // C/2 hidden dim

// Kernel 0: per-group view weights and mask counts.
// scale[g*V+v] = is_seen[v,n] / (sum_v is_seen[v,n] + 1e-6);  mcnt[m] += 1
__global__ void scale_kernel(const float* __restrict__ is_seen,
                             const int* __restrict__ centers,
                             const int* __restrict__ g2m,
                             float* __restrict__ scale,
                             float* __restrict__ mcnt) {
  int g = blockIdx.x * blockDim.x + threadIdx.x;
  if (g >= G_) return;
  int n = centers[g];
  float w[V_];
  float wsum = 0.f;
#pragma unroll
  for (int v = 0; v < V_; ++v) {
    w[v] = is_seen[(size_t)v * N_ + n];
    wsum += w[v];
  }
  float inv = 1.0f / (wsum + 1e-6f);
#pragma unroll
  for (int v = 0; v < V_; ++v) scale[(size_t)g * V_ + v] = w[v] * inv;
  atomicAdd(&mcnt[g2m[g]], 1.0f);
}

// Kernel 1: view-major gather. One block per (v,g); v is the SLOW dispatch
// coordinate so all 4096 blocks of a view are co-resident -> per-view img
// line footprint (~16.5 MB) is L3/L2-resident and line reuse is captured.
// Accumulates the already-normalized point feature directly into msum[m].
__global__ void gather_mask_kernel(const float* __restrict__ img,
                                   const int* __restrict__ coords,
                                   const int* __restrict__ centers,
                                   const int* __restrict__ g2m,
                                   const float* __restrict__ scale,
                                   float* __restrict__ msum) {
  int bid = blockIdx.x;
  int v = bid / G_;        // slow: views dispatch sequentially
  int g = bid - v * G_;
  int c = threadIdx.x;     // 0..C-1
  int n = centers[g];
  int m = g2m[g];
  float s = scale[(size_t)g * V_ + v];
  int x = coords[((size_t)v * N_ + n) * 2 + 0];
  int y = coords[((size_t)v * N_ + n) * 2 + 1];
  float f = img[(((size_t)v * C_ + c) * H_ + y) * W_ + x];
  atomicAdd(&msum[(size_t)m * C_ + c], f * s);
}

// Kernel 2: mW1[m] = (where(mcnt>0, msum/max(mcnt,1), 0)) @ W1   (512 x 128)
__global__ void maskw1_kernel(const float* __restrict__ msum,
                              const float* __restrict__ mcnt,
                              const float* __restrict__ W1,
                              float* __restrict__ mW1) {
  int m = blockIdx.x;        // 0..M-1
  int j = threadIdx.x;       // 0..HD-1
  __shared__ float row[C_];
  row[j] = msum[(size_t)m * C_ + j];
  row[j + HD] = msum[(size_t)m * C_ + j + HD];
  __syncthreads();
  float cv = mcnt[m];
  float inv = cv > 0.f ? 1.0f / fmaxf(cv, 1.0f) : 0.f;
  float acc = 0.f;
  for (int c = 0; c < C_; ++c) {
    acc += row[c] * W1[(size_t)c * HD + j];
  }
  mW1[(size_t)m * HD + j] = acc * inv;
}

// Kernel 3: scatter pairs: fsum[p] += mW1[pair_mask[e]] ; cnt[p] += 1
__global__ void scatter_kernel(const int* __restrict__ pair_mask,
                               const int* __restrict__ pair_point,
                               const float* __restrict__ mW1,
                               float* __restrict__ fsum,
                               float* __restrict__ cnt) {
  int e = blockIdx.x;        // 0..E-1
  int j = threadIdx.x;       // 0..HD-1
  int m = pair_mask[e];
  int p = pair_point[e];
  atomicAdd(&fsum[(size_t)p * HD + j], mW1[(size_t)m * HD + j]);
  if (j == 0) atomicAdd(&cnt[p], 1.0f);
}

// Kernel 4: per-point epilogue: h = relu(fsum/cnt + b1); out = h @ W2 + b2
__global__ void mlp_kernel(const float* __restrict__ fsum,
                           const float* __restrict__ cnt,
                           const float* __restrict__ b1,
                           const float* __restrict__ W2,
                           const float* __restrict__ b2,
                           float* __restrict__ out) {
  int n = blockIdx.x * blockDim.x + threadIdx.x;
  if (n >= N_) return;
  float invc = 1.0f / fmaxf(cnt[n], 1e-6f);
  float o[L_];
#pragma unroll
  for (int l = 0; l < L_; ++l) o[l] = b2[l];
  const float* xr = &fsum[(size_t)n * HD];
#pragma unroll 4
  for (int k = 0; k < HD; ++k) {
    float h = fmaxf(xr[k] * invc + b1[k], 0.f);
#pragma unroll
    for (int l = 0; l < L_; ++l) o[l] += h * W2[k * L_ + l];
  }
  float* dst = &out[(size_t)n * L_];
#pragma unroll
  for (int l = 0; l < L_; ++l) dst[l] = o[l];
}

extern "C" void kernel_launch(void* const* d_in, const int* in_sizes, int n_in,
                              void* d_out, int out_size, void* d_ws, size_t ws_size,
                              hipStream_t stream) {
  const float* img      = (const float*)d_in[0];
  const float* is_seen  = (const float*)d_in[1];
  const float* W1       = (const float*)d_in[2];
  const float* b1       = (const float*)d_in[3];
  const float* W2       = (const float*)d_in[4];
  const float* b2       = (const float*)d_in[5];
  const int* coords     = (const int*)d_in[6];
  const int* centers    = (const int*)d_in[7];
  const int* g2m        = (const int*)d_in[8];
  const int* pair_mask  = (const int*)d_in[9];
  const int* pair_point = (const int*)d_in[10];
  float* out = (float*)d_out;

  // Workspace (floats): msum[M*C] | mcnt[M] | mW1[M*HD] | fsum[N*HD] | cnt[N] | scale[G*V]
  float* ws    = (float*)d_ws;
  float* msum  = ws;
  float* mcnt  = msum + (size_t)M_ * C_;
  float* mW1   = mcnt + M_;
  float* fsum  = mW1 + (size_t)M_ * HD;
  float* cnt   = fsum + (size_t)N_ * HD;
  float* scale = cnt + N_;

  // Zero the accumulators (stream memsets; must run every call)
  hipMemsetAsync(msum, 0, ((size_t)M_ * C_ + M_) * sizeof(float), stream);
  hipMemsetAsync(fsum, 0, ((size_t)N_ * HD + N_) * sizeof(float), stream);

  scale_kernel<<<(G_ + 255) / 256, 256, 0, stream>>>(is_seen, centers, g2m, scale, mcnt);
  gather_mask_kernel<<<G_ * V_, C_, 0, stream>>>(img, coords, centers, g2m, scale, msum);
  maskw1_kernel<<<M_, HD, 0, stream>>>(msum, mcnt, W1, mW1);
  scatter_kernel<<<E_, HD, 0, stream>>>(pair_mask, pair_point, mW1, fsum, cnt);
  mlp_kernel<<<(N_ + 255) / 256, 256, 0, stream>>>(fsum, cnt, b1, W2, b2, out);
}

// Round 3
// 203.487 us; speedup vs baseline: 1.8183x; 1.6664x over previous
//
#include <hip/hip_runtime.h>

// Problem constants (from reference)
#define V_ 12
#define N_ 80000
#define C_ 256
#define H_ 128
#define W_ 128
#define G_ 4096
#define M_ 512
#define E_ 200000
#define L_ 20
#define HD 128            // C/2 hidden dim
#define NBUCK (V_ * 1024) // line-buckets: (v, y, x>>4) ; 1024 = 128*8 per view
#define BCAP 32           // max group-items per line-bucket (Poisson λ=4; P(>=32)~1e-16)
#define PCAP 32           // max pairs per point (Poisson λ=2.5; P(>=32)~1e-19)
#define GV (G_ * V_)

// ---------------------------------------------------------------------------
// Kernel 1: build both inverted indexes in one pass.
//  t < GV          : (g,v) item -> line-bucket b=(v,y,x>>4); store {m, x&15, scale}
//  GV <= t < GV+E  : pair e -> per-point list; store mask id
// Also accumulates mcnt[m] (groups per mask) from the v==0 thread of each g.
__global__ void build_kernel(const float* __restrict__ is_seen,
                             const int* __restrict__ coords,
                             const int* __restrict__ centers,
                             const int* __restrict__ g2m,
                             const int* __restrict__ pair_mask,
                             const int* __restrict__ pair_point,
                             int* __restrict__ bcount,
                             int* __restrict__ bmeta,
                             float* __restrict__ bscale,
                             int* __restrict__ pcount,
                             int* __restrict__ pitems,
                             float* __restrict__ mcnt) {
  int t = blockIdx.x * blockDim.x + threadIdx.x;
  if (t < GV) {
    int g = t & (G_ - 1);   // g fast -> coalesced-ish centers reads
    int v = t >> 12;
    int n = centers[g];
    float wsum = 0.f;
#pragma unroll
    for (int vv = 0; vv < V_; ++vv) wsum += is_seen[(size_t)vv * N_ + n];
    float s = is_seen[(size_t)v * N_ + n] / (wsum + 1e-6f);
    int m = g2m[g];
    if (v == 0) atomicAdd(&mcnt[m], 1.0f);
    int x = coords[((size_t)v * N_ + n) * 2 + 0];
    int y = coords[((size_t)v * N_ + n) * 2 + 1];
    int b = (v << 10) | (y << 3) | (x >> 4);
    int slot = atomicAdd(&bcount[b], 1);
    if (slot < BCAP) {
      bmeta[b * BCAP + slot] = m | ((x & 15) << 9);  // m:9 bits, xi:4 bits
      bscale[b * BCAP + slot] = s;
    }
  } else if (t < GV + E_) {
    int e = t - GV;
    int p = pair_point[e];
    int slot = atomicAdd(&pcount[p], 1);
    if (slot < PCAP) pitems[(size_t)p * PCAP + slot] = pair_mask[e];
  }
}

// ---------------------------------------------------------------------------
// Kernel 2: line-bucket gather. One block per (v,y,x>>4) bucket; thread c owns
// channel c. Each needed 64B img line is read EXACTLY ONCE (4x float4), parked
// in LDS (stride 17 -> conflict-free), then distributed to all groups that
// hit this bucket. Accumulates scaled features into msum[m] via atomics.
__global__ void gather_kernel(const float* __restrict__ img,
                              const int* __restrict__ bcount,
                              const int* __restrict__ bmeta,
                              const float* __restrict__ bscale,
                              float* __restrict__ msum) {
  int b = blockIdx.x;
  int cnt = bcount[b];
  if (cnt == 0) return;
  if (cnt > BCAP) cnt = BCAP;
  int c = threadIdx.x;              // 0..255
  int v = b >> 10;
  int y = (b >> 3) & 127;
  int x0 = (b & 7) << 4;
  __shared__ float lines[C_ * 17];  // per-thread 16 floats, stride 17
  const float4* src = (const float4*)(img + (((size_t)(v * C_ + c)) * H_ + y) * W_ + x0);
  float4 q0 = src[0], q1 = src[1], q2 = src[2], q3 = src[3];
  float* lr = &lines[c * 17];
  lr[0] = q0.x; lr[1] = q0.y; lr[2] = q0.z; lr[3] = q0.w;
  lr[4] = q1.x; lr[5] = q1.y; lr[6] = q1.z; lr[7] = q1.w;
  lr[8] = q2.x; lr[9] = q2.y; lr[10] = q2.z; lr[11] = q2.w;
  lr[12] = q3.x; lr[13] = q3.y; lr[14] = q3.z; lr[15] = q3.w;
  // Only the owning thread reads its own lr[] -> no __syncthreads needed.
  for (int it = 0; it < cnt; ++it) {
    int meta = bmeta[b * BCAP + it];
    float s = bscale[b * BCAP + it];
    int m = meta & 511;
    int xi = (meta >> 9) & 15;
    atomicAdd(&msum[(size_t)m * C_ + c], lr[xi] * s);
  }
}

// ---------------------------------------------------------------------------
// Kernel 3: mW1[m] = (where(mcnt>0, msum/max(mcnt,1), 0)) @ W1   (512 x 128)
__global__ void maskw1_kernel(const float* __restrict__ msum,
                              const float* __restrict__ mcnt,
                              const float* __restrict__ W1,
                              float* __restrict__ mW1) {
  int m = blockIdx.x;        // 0..M-1
  int j = threadIdx.x;       // 0..HD-1
  __shared__ float row[C_];
  row[j] = msum[(size_t)m * C_ + j];
  row[j + HD] = msum[(size_t)m * C_ + j + HD];
  __syncthreads();
  float cv = mcnt[m];
  float inv = cv > 0.f ? 1.0f / fmaxf(cv, 1.0f) : 0.f;
  float acc = 0.f;
  for (int c = 0; c < C_; ++c) {
    acc += row[c] * W1[(size_t)c * HD + j];
  }
  mW1[(size_t)m * HD + j] = acc * inv;
}

// ---------------------------------------------------------------------------
// Kernel 4: one wave per point. Gather & sum the point's mW1 rows (avg 2.5,
// L2-resident 256KB table), relu(mean + b1) into LDS, then 20 lanes do the
// 128x20 layer-2 matvec and write the 20 outputs. No atomics, no fsum buffer.
__global__ void point_mlp_kernel(const int* __restrict__ pcount,
                                 const int* __restrict__ pitems,
                                 const float* __restrict__ mW1,
                                 const float* __restrict__ b1,
                                 const float* __restrict__ W2,
                                 const float* __restrict__ b2,
                                 float* __restrict__ out) {
  int wave = threadIdx.x >> 6;
  int lane = threadIdx.x & 63;
  int p = blockIdx.x * 4 + wave;   // N = 80000 = 20000*4 exactly
  __shared__ float hbuf[4][130];
  int cnt = pcount[p];
  int k = cnt < PCAP ? cnt : PCAP;
  float hx = 0.f, hy = 0.f;
  const int* lst = &pitems[(size_t)p * PCAP];
  for (int it = 0; it < k; ++it) {
    int m = lst[it];
    float2 r = ((const float2*)(mW1 + (size_t)m * HD))[lane];
    hx += r.x;
    hy += r.y;
  }
  float invc = 1.0f / fmaxf((float)cnt, 1e-6f);
  hbuf[wave][2 * lane]     = fmaxf(hx * invc + b1[2 * lane], 0.f);
  hbuf[wave][2 * lane + 1] = fmaxf(hy * invc + b1[2 * lane + 1], 0.f);
  __syncthreads();
  if (lane < L_) {
    float o = b2[lane];
    const float* hb = hbuf[wave];
#pragma unroll 8
    for (int kk = 0; kk < HD; ++kk) o += hb[kk] * W2[kk * L_ + lane];
    out[(size_t)p * L_ + lane] = o;
  }
}

// ---------------------------------------------------------------------------
extern "C" void kernel_launch(void* const* d_in, const int* in_sizes, int n_in,
                              void* d_out, int out_size, void* d_ws, size_t ws_size,
                              hipStream_t stream) {
  const float* img      = (const float*)d_in[0];
  const float* is_seen  = (const float*)d_in[1];
  const float* W1       = (const float*)d_in[2];
  const float* b1       = (const float*)d_in[3];
  const float* W2       = (const float*)d_in[4];
  const float* b2       = (const float*)d_in[5];
  const int* coords     = (const int*)d_in[6];
  const int* centers    = (const int*)d_in[7];
  const int* g2m        = (const int*)d_in[8];
  const int* pair_mask  = (const int*)d_in[9];
  const int* pair_point = (const int*)d_in[10];
  float* out = (float*)d_out;

  // Workspace layout:
  // floats: msum[M*C] | mcnt[M] | mW1[M*HD] | bscale[NBUCK*BCAP]
  // ints  : bcount[NBUCK] | pcount[N] | bmeta[NBUCK*BCAP] | pitems[N*PCAP]
  float* ws     = (float*)d_ws;
  float* msum   = ws;
  float* mcnt   = msum + (size_t)M_ * C_;
  float* mW1    = mcnt + M_;
  float* bscale = mW1 + (size_t)M_ * HD;
  int*   bcount = (int*)(bscale + (size_t)NBUCK * BCAP);
  int*   pcount = bcount + NBUCK;
  int*   bmeta  = pcount + N_;
  int*   pitems = bmeta + (size_t)NBUCK * BCAP;

  // Zero accumulators + counters (2 contiguous memsets; run every call)
  hipMemsetAsync(msum, 0, ((size_t)M_ * C_ + M_) * sizeof(float), stream);
  hipMemsetAsync(bcount, 0, ((size_t)NBUCK + N_) * sizeof(int), stream);

  build_kernel<<<(GV + E_ + 255) / 256, 256, 0, stream>>>(
      is_seen, coords, centers, g2m, pair_mask, pair_point,
      bcount, bmeta, bscale, pcount, pitems, mcnt);
  gather_kernel<<<NBUCK, C_, 0, stream>>>(img, bcount, bmeta, bscale, msum);
  maskw1_kernel<<<M_, HD, 0, stream>>>(msum, mcnt, W1, mW1);
  point_mlp_kernel<<<N_ / 4, 256, 0, stream>>>(pcount, pitems, mW1, b1, W2, b2, out);
}